// Round 1
// baseline (1983.382 us; speedup 1.0000x reference)
//
#include <hip/hip_runtime.h>

#define NN 100000
#define NE 1200000
#define NG 512

// ---- workspace layout (bytes) ----
static constexpr size_t AGG_BYTES = (size_t)3 * NN * 64 * 4;          // 76,800,000
static constexpr size_t AGG_OFF   = 0;
static constexpr size_t CNT_OFF   = AGG_OFF + AGG_BYTES;              // 3*NN ints
static constexpr size_t POOL_OFF  = CNT_OFF + (size_t)3 * NN * 4;     // NG*64 floats
static constexpr size_t GCNT_OFF  = POOL_OFF + (size_t)NG * 64 * 4;   // NG ints
static constexpr size_t H0_OFF    = GCNT_OFF + 4096;                  // NN*32 floats
static constexpr size_t H1_OFF    = H0_OFF + (size_t)NN * 32 * 4;     // NN*64 floats
static constexpr size_t H2_OFF    = H1_OFF + (size_t)NN * 64 * 4;     // NN*64 floats
static constexpr size_t ZERO1_BYTES = GCNT_OFF + (size_t)NG * 4;      // agg+cnt+pool+gcnt

// ---- node embedding + pre MLP: h0[n][32] = relu(concat(se[x0],ce[x1]) @ pre_w + pre_b)
__global__ __launch_bounds__(256)
void k_embed_pre(const int* __restrict__ x, const float* __restrict__ se,
                 const float* __restrict__ ce, const float* __restrict__ pw,
                 const float* __restrict__ pb, float* __restrict__ h0) {
    __shared__ float sW[16 * 32];
    __shared__ float sB[32];
    for (int i = threadIdx.x; i < 512; i += blockDim.x) sW[i] = pw[i];
    if (threadIdx.x < 32) sB[threadIdx.x] = pb[threadIdx.x];
    __syncthreads();
    int n = blockIdx.x * blockDim.x + threadIdx.x;
    if (n >= NN) return;
    int si = x[2 * n], ci = x[2 * n + 1];
    float in[16];
#pragma unroll
    for (int k = 0; k < 8; k++) in[k] = se[si * 8 + k];
#pragma unroll
    for (int k = 0; k < 8; k++) in[8 + k] = ce[ci * 8 + k];
    float acc[32];
#pragma unroll
    for (int j = 0; j < 32; j++) acc[j] = sB[j];
#pragma unroll
    for (int k = 0; k < 16; k++) {
        float hv = in[k];
#pragma unroll
        for (int j = 0; j < 32; j++) acc[j] += hv * sW[k * 32 + j];
    }
    float* o = h0 + (size_t)n * 32;
#pragma unroll
    for (int j = 0; j < 32; j += 4) {
        float4 v = make_float4(fmaxf(acc[j], 0.f), fmaxf(acc[j + 1], 0.f),
                               fmaxf(acc[j + 2], 0.f), fmaxf(acc[j + 3], 0.f));
        *(float4*)(o + j) = v;
    }
}

// ---- per-(rel,dst) edge counts
__global__ __launch_bounds__(256)
void k_count(const int* __restrict__ ei, const int* __restrict__ et, int* __restrict__ cnt) {
    int e = blockIdx.x * blockDim.x + threadIdx.x;
    if (e >= NE) return;
    int d = ei[NE + e];
    int r = et[e];
    atomicAdd(&cnt[r * NN + d], 1);
}

// ---- scatter: agg[r][dst][0:C] += h[src][0:C], P = C/4 threads per edge
template <int C>
__global__ __launch_bounds__(256)
void k_scatter(const int* __restrict__ ei, const int* __restrict__ et,
               const float* __restrict__ h, float* __restrict__ agg) {
    constexpr int P = C / 4;
    int tid = blockIdx.x * blockDim.x + threadIdx.x;
    int e = tid / P;
    int p = tid % P;
    if (e >= NE) return;
    int s = ei[e], d = ei[NE + e], r = et[e];
    float4 v = *(const float4*)(h + (size_t)s * C + p * 4);
    float* dp = agg + ((size_t)r * NN + d) * C + p * 4;
    atomicAdd(dp + 0, v.x);
    atomicAdd(dp + 1, v.y);
    atomicAdd(dp + 2, v.z);
    atomicAdd(dp + 3, v.w);
}

__device__ inline void fma4(float4& a, const float4 h, const float4 w0, const float4 w1,
                            const float4 w2, const float4 w3) {
    a.x += h.x * w0.x + h.y * w1.x + h.z * w2.x + h.w * w3.x;
    a.y += h.x * w0.y + h.y * w1.y + h.z * w2.y + h.w * w3.y;
    a.z += h.x * w0.z + h.y * w1.z + h.z * w2.z + h.w * w3.z;
    a.w += h.x * w0.w + h.y * w1.w + h.z * w2.w + h.w * w3.w;
}

// ---- combine: h_out[n][j] = relu(b[j] + h_in[n]@root[:,j] + sum_r (agg_r[n]/cnt_r[n])@W_r[:,j])
// thread = (node, 4 consecutive output cols)
template <int CIN>
__global__ __launch_bounds__(256)
void k_combine(const float* __restrict__ h_in, const float* __restrict__ agg,
               const int* __restrict__ cnt, const float* __restrict__ root,
               const float* __restrict__ w, const float* __restrict__ bias,
               float* __restrict__ h_out) {
    int t = blockIdx.x * blockDim.x + threadIdx.x;
    int n = t >> 4;
    if (n >= NN) return;
    int j4 = (t & 15) << 2;
    float4 acc = *(const float4*)(bias + j4);
    {
        const float* hr = h_in + (size_t)n * CIN;
#pragma unroll
        for (int k = 0; k < CIN; k += 4) {
            float4 hv = *(const float4*)(hr + k);
            float4 w0 = *(const float4*)(root + (k + 0) * 64 + j4);
            float4 w1v = *(const float4*)(root + (k + 1) * 64 + j4);
            float4 w2v = *(const float4*)(root + (k + 2) * 64 + j4);
            float4 w3v = *(const float4*)(root + (k + 3) * 64 + j4);
            fma4(acc, hv, w0, w1v, w2v, w3v);
        }
    }
#pragma unroll
    for (int r = 0; r < 3; r++) {
        const float* ar = agg + ((size_t)r * NN + n) * CIN;
        const float* wr = w + r * CIN * 64;
        float4 racc = make_float4(0.f, 0.f, 0.f, 0.f);
#pragma unroll
        for (int k = 0; k < CIN; k += 4) {
            float4 hv = *(const float4*)(ar + k);
            float4 w0 = *(const float4*)(wr + (k + 0) * 64 + j4);
            float4 w1v = *(const float4*)(wr + (k + 1) * 64 + j4);
            float4 w2v = *(const float4*)(wr + (k + 2) * 64 + j4);
            float4 w3v = *(const float4*)(wr + (k + 3) * 64 + j4);
            fma4(racc, hv, w0, w1v, w2v, w3v);
        }
        int c = cnt[r * NN + n];
        float inv = 1.f / (float)(c > 1 ? c : 1);
        acc.x += racc.x * inv;
        acc.y += racc.y * inv;
        acc.z += racc.z * inv;
        acc.w += racc.w * inv;
    }
    float4 o = make_float4(fmaxf(acc.x, 0.f), fmaxf(acc.y, 0.f),
                           fmaxf(acc.z, 0.f), fmaxf(acc.w, 0.f));
    *(float4*)(h_out + (size_t)n * 64 + j4) = o;
}

// ---- per-graph node counts via binary search on sorted batch (no atomics)
__global__ __launch_bounds__(256)
void k_gcnt(const int* __restrict__ batch, int* __restrict__ gcnt) {
    int g = blockIdx.x * blockDim.x + threadIdx.x;
    if (g >= NG) return;
    auto lb = [&](int v) {
        int lo = 0, hi = NN;
        while (lo < hi) {
            int m = (lo + hi) >> 1;
            if (batch[m] < v) lo = m + 1; else hi = m;
        }
        return lo;
    };
    gcnt[g] = lb(g + 1) - lb(g);
}

// ---- mean pool scatter: pool[batch[n]][j] += h2[n][j]
__global__ __launch_bounds__(256)
void k_pool(const float* __restrict__ h, const int* __restrict__ batch,
            float* __restrict__ pool) {
    int t = blockIdx.x * blockDim.x + threadIdx.x;
    int n = t >> 6;
    if (n >= NN) return;
    int j = t & 63;
    atomicAdd(&pool[batch[n] * 64 + j], h[(size_t)n * 64 + j]);
}

// ---- classifier: out[g][j] = cls_b[j] + (pool[g]/gcnt[g]) @ cls_w[:,j]
__global__ __launch_bounds__(256)
void k_final(const float* __restrict__ pool, const int* __restrict__ gcnt,
             const float* __restrict__ cw, const float* __restrict__ cb,
             float* __restrict__ out) {
    int t = blockIdx.x * blockDim.x + threadIdx.x;
    if (t >= NG * 10) return;
    int g = t / 10, j = t % 10;
    int c = gcnt[g];
    float inv = 1.f / (float)(c > 1 ? c : 1);
    float acc = 0.f;
#pragma unroll
    for (int k = 0; k < 64; k++) acc += pool[g * 64 + k] * cw[k * 10 + j];
    out[t] = cb[j] + acc * inv;
}

extern "C" void kernel_launch(void* const* d_in, const int* in_sizes, int n_in,
                              void* d_out, int out_size, void* d_ws, size_t ws_size,
                              hipStream_t stream) {
    const int* x      = (const int*)d_in[0];
    const int* ei     = (const int*)d_in[1];
    const int* et     = (const int*)d_in[2];
    const int* batch  = (const int*)d_in[3];
    const float* se   = (const float*)d_in[4];
    const float* ce   = (const float*)d_in[5];
    const float* pw   = (const float*)d_in[6];
    const float* pb   = (const float*)d_in[7];
    const float* w1   = (const float*)d_in[8];
    const float* root1= (const float*)d_in[9];
    const float* b1   = (const float*)d_in[10];
    const float* w2   = (const float*)d_in[11];
    const float* root2= (const float*)d_in[12];
    const float* b2   = (const float*)d_in[13];
    const float* cw   = (const float*)d_in[14];
    const float* cb   = (const float*)d_in[15];
    float* out = (float*)d_out;

    char* ws = (char*)d_ws;
    float* agg  = (float*)(ws + AGG_OFF);
    int*   cnt  = (int*)(ws + CNT_OFF);
    float* pool = (float*)(ws + POOL_OFF);
    int*   gcnt = (int*)(ws + GCNT_OFF);
    float* h0   = (float*)(ws + H0_OFF);
    float* h1   = (float*)(ws + H1_OFF);
    float* h2   = (float*)(ws + H2_OFF);

    // zero agg + cnt + pool (+gcnt)
    hipMemsetAsync(ws, 0, ZERO1_BYTES, stream);

    k_embed_pre<<<(NN + 255) / 256, 256, 0, stream>>>(x, se, ce, pw, pb, h0);
    k_count<<<(NE + 255) / 256, 256, 0, stream>>>(ei, et, cnt);

    // layer 1
    k_scatter<32><<<(NE * 8 + 255) / 256, 256, 0, stream>>>(ei, et, h0, agg);
    k_combine<32><<<(NN * 16 + 255) / 256, 256, 0, stream>>>(h0, agg, cnt, root1, w1, b1, h1);

    // layer 2
    hipMemsetAsync(agg, 0, AGG_BYTES, stream);
    k_scatter<64><<<(NE * 16 + 255) / 256, 256, 0, stream>>>(ei, et, h1, agg);
    k_combine<64><<<(NN * 16 + 255) / 256, 256, 0, stream>>>(h1, agg, cnt, root2, w2, b2, h2);

    // pooling + classifier
    k_gcnt<<<(NG + 255) / 256, 256, 0, stream>>>(batch, gcnt);
    k_pool<<<(NN * 64 + 255) / 256, 256, 0, stream>>>(h2, batch, pool);
    k_final<<<(NG * 10 + 255) / 256, 256, 0, stream>>>(pool, gcnt, cw, cb, out);
}

// Round 2
// 632.787 us; speedup vs baseline: 3.1344x; 3.1344x over previous
//
#include <hip/hip_runtime.h>

#define NN 100000
#define NE 1200000
#define NG 512
#define NSEG (3 * NN)
#define CHUNK 1024
#define NCHUNK ((NSEG + CHUNK - 1) / CHUNK)

// ---- workspace layout (bytes), all 16B-aligned ----
static constexpr size_t AGG_OFF   = 0;                                  // 3*NN*64 f32
static constexpr size_t AGG_BYTES = (size_t)NSEG * 64 * 4;              // 76,800,000
static constexpr size_t CUR_OFF   = AGG_OFF + AGG_BYTES;                // NSEG ints (hist -> cursor)
static constexpr size_t START_OFF = CUR_OFF + (size_t)NSEG * 4;         // NSEG ints
static constexpr size_t CSUM_OFF  = START_OFF + (size_t)NSEG * 4;       // NCHUNK ints
static constexpr size_t ESRC_OFF  = CSUM_OFF + 4096;                    // NE ints
static constexpr size_t POOL_OFF  = ESRC_OFF + (size_t)NE * 4;          // NG*64 f32
static constexpr size_t H0_OFF    = POOL_OFF + (size_t)NG * 64 * 4;     // NN*32 f32
static constexpr size_t H1_OFF    = H0_OFF + (size_t)NN * 32 * 4;       // NN*64 f32
static constexpr size_t H2_OFF    = H1_OFF + (size_t)NN * 64 * 4;       // NN*64 f32

// ---- node embedding + pre MLP: h0[n][32] = relu(concat(se[x0],ce[x1]) @ pre_w + pre_b)
__global__ __launch_bounds__(256)
void k_embed_pre(const int* __restrict__ x, const float* __restrict__ se,
                 const float* __restrict__ ce, const float* __restrict__ pw,
                 const float* __restrict__ pb, float* __restrict__ h0) {
    __shared__ float sW[16 * 32];
    __shared__ float sB[32];
    for (int i = threadIdx.x; i < 512; i += blockDim.x) sW[i] = pw[i];
    if (threadIdx.x < 32) sB[threadIdx.x] = pb[threadIdx.x];
    __syncthreads();
    int n = blockIdx.x * blockDim.x + threadIdx.x;
    if (n >= NN) return;
    int si = x[2 * n], ci = x[2 * n + 1];
    float in[16];
#pragma unroll
    for (int k = 0; k < 8; k++) in[k] = se[si * 8 + k];
#pragma unroll
    for (int k = 0; k < 8; k++) in[8 + k] = ce[ci * 8 + k];
    float acc[32];
#pragma unroll
    for (int j = 0; j < 32; j++) acc[j] = sB[j];
#pragma unroll
    for (int k = 0; k < 16; k++) {
        float hv = in[k];
#pragma unroll
        for (int j = 0; j < 32; j++) acc[j] += hv * sW[k * 32 + j];
    }
    float* o = h0 + (size_t)n * 32;
#pragma unroll
    for (int j = 0; j < 32; j += 4) {
        float4 v = make_float4(fmaxf(acc[j], 0.f), fmaxf(acc[j + 1], 0.f),
                               fmaxf(acc[j + 2], 0.f), fmaxf(acc[j + 3], 0.f));
        *(float4*)(o + j) = v;
    }
}

// ---- histogram per (rel,dst) segment (into cur[], int atomics)
__global__ __launch_bounds__(256)
void k_count(const int* __restrict__ ei, const int* __restrict__ et, int* __restrict__ hist) {
    int e = blockIdx.x * blockDim.x + threadIdx.x;
    if (e >= NE) return;
    int d = ei[NE + e];
    int r = et[e];
    atomicAdd(&hist[r * NN + d], 1);
}

// ---- scan pass 1: per-chunk sums
__global__ __launch_bounds__(256)
void k_chunksum(const int* __restrict__ hist, int* __restrict__ csum) {
    __shared__ int s[256];
    int b = blockIdx.x, t = threadIdx.x;
    int base = b * CHUNK + t * 4;
    int sum = 0;
#pragma unroll
    for (int k = 0; k < 4; k++) {
        int i = base + k;
        if (i < NSEG) sum += hist[i];
    }
    s[t] = sum;
    __syncthreads();
    for (int off = 128; off > 0; off >>= 1) {
        if (t < off) s[t] += s[t + off];
        __syncthreads();
    }
    if (t == 0) csum[b] = s[0];
}

// ---- scan pass 2: exclusive scan of chunk sums (tiny, single thread)
__global__ void k_chunkscan(int* __restrict__ csum) {
    if (blockIdx.x == 0 && threadIdx.x == 0) {
        int run = 0;
        for (int i = 0; i < NCHUNK; i++) {
            int v = csum[i];
            csum[i] = run;
            run += v;
        }
    }
}

// ---- scan pass 3: local exclusive scan; writes start[] and re-inits cur[] (cursor)
__global__ __launch_bounds__(256)
void k_localscan(int* __restrict__ hist_cur, const int* __restrict__ csum,
                 int* __restrict__ start) {
    __shared__ int s[256];
    int b = blockIdx.x, t = threadIdx.x;
    int base = b * CHUNK + t * 4;
    int v[4];
    int s4 = 0;
#pragma unroll
    for (int k = 0; k < 4; k++) {
        int i = base + k;
        v[k] = (i < NSEG) ? hist_cur[i] : 0;
        s4 += v[k];
    }
    s[t] = s4;
    __syncthreads();
    for (int off = 1; off < 256; off <<= 1) {
        int x = (t >= off) ? s[t - off] : 0;
        __syncthreads();
        s[t] += x;
        __syncthreads();
    }
    int excl = s[t] - s4 + csum[b];
#pragma unroll
    for (int k = 0; k < 4; k++) {
        int i = base + k;
        if (i < NSEG) {
            start[i] = excl;
            hist_cur[i] = excl;  // cursor for fill
        }
        excl += v[k];
    }
}

// ---- fill CSR edge array (src ids), int-atomic cursors
__global__ __launch_bounds__(256)
void k_fill(const int* __restrict__ ei, const int* __restrict__ et,
            int* __restrict__ cur, int* __restrict__ esrc) {
    int e = blockIdx.x * blockDim.x + threadIdx.x;
    if (e >= NE) return;
    int s = ei[e], d = ei[NE + e], r = et[e];
    int pos = atomicAdd(&cur[r * NN + d], 1);
    esrc[pos] = s;
}

// ---- gather-aggregate: agg[seg][0:C] = sum_{edges in seg} h[src][0:C] (no atomics)
template <int C>
__global__ __launch_bounds__(256)
void k_gather(const int* __restrict__ start, const int* __restrict__ cur,
              const int* __restrict__ esrc, const float* __restrict__ h,
              float* __restrict__ agg) {
    constexpr int P = C / 4;
    int tid = blockIdx.x * blockDim.x + threadIdx.x;
    int seg = tid / P;
    int p = tid % P;
    if (seg >= NSEG) return;
    int st = start[seg], en = cur[seg];
    float4 acc = make_float4(0.f, 0.f, 0.f, 0.f);
    for (int i = st; i < en; i++) {
        int s = esrc[i];
        float4 v = *(const float4*)(h + (size_t)s * C + p * 4);
        acc.x += v.x; acc.y += v.y; acc.z += v.z; acc.w += v.w;
    }
    *(float4*)(agg + (size_t)seg * C + p * 4) = acc;
}

__device__ inline void fma4(float4& a, const float4 h, const float4 w0, const float4 w1,
                            const float4 w2, const float4 w3) {
    a.x += h.x * w0.x + h.y * w1.x + h.z * w2.x + h.w * w3.x;
    a.y += h.x * w0.y + h.y * w1.y + h.z * w2.y + h.w * w3.y;
    a.z += h.x * w0.z + h.y * w1.z + h.z * w2.z + h.w * w3.z;
    a.w += h.x * w0.w + h.y * w1.w + h.z * w2.w + h.w * w3.w;
}

// ---- combine: h_out[n][j] = relu(b[j] + h_in[n]@root[:,j] + sum_r (agg_r[n]/deg_r[n])@W_r[:,j])
template <int CIN>
__global__ __launch_bounds__(256)
void k_combine(const float* __restrict__ h_in, const float* __restrict__ agg,
               const int* __restrict__ start, const int* __restrict__ cur,
               const float* __restrict__ root, const float* __restrict__ w,
               const float* __restrict__ bias, float* __restrict__ h_out) {
    int t = blockIdx.x * blockDim.x + threadIdx.x;
    int n = t >> 4;
    if (n >= NN) return;
    int j4 = (t & 15) << 2;
    float4 acc = *(const float4*)(bias + j4);
    {
        const float* hr = h_in + (size_t)n * CIN;
#pragma unroll
        for (int k = 0; k < CIN; k += 4) {
            float4 hv = *(const float4*)(hr + k);
            float4 w0 = *(const float4*)(root + (k + 0) * 64 + j4);
            float4 w1v = *(const float4*)(root + (k + 1) * 64 + j4);
            float4 w2v = *(const float4*)(root + (k + 2) * 64 + j4);
            float4 w3v = *(const float4*)(root + (k + 3) * 64 + j4);
            fma4(acc, hv, w0, w1v, w2v, w3v);
        }
    }
#pragma unroll
    for (int r = 0; r < 3; r++) {
        int seg = r * NN + n;
        const float* ar = agg + (size_t)seg * CIN;
        const float* wr = w + r * CIN * 64;
        float4 racc = make_float4(0.f, 0.f, 0.f, 0.f);
#pragma unroll
        for (int k = 0; k < CIN; k += 4) {
            float4 hv = *(const float4*)(ar + k);
            float4 w0 = *(const float4*)(wr + (k + 0) * 64 + j4);
            float4 w1v = *(const float4*)(wr + (k + 1) * 64 + j4);
            float4 w2v = *(const float4*)(wr + (k + 2) * 64 + j4);
            float4 w3v = *(const float4*)(wr + (k + 3) * 64 + j4);
            fma4(racc, hv, w0, w1v, w2v, w3v);
        }
        int c = cur[seg] - start[seg];
        float inv = 1.f / (float)(c > 1 ? c : 1);
        acc.x += racc.x * inv;
        acc.y += racc.y * inv;
        acc.z += racc.z * inv;
        acc.w += racc.w * inv;
    }
    float4 o = make_float4(fmaxf(acc.x, 0.f), fmaxf(acc.y, 0.f),
                           fmaxf(acc.z, 0.f), fmaxf(acc.w, 0.f));
    *(float4*)(h_out + (size_t)n * 64 + j4) = o;
}

// ---- mean pool via binary search on sorted batch (no atomics); writes mean directly
__global__ __launch_bounds__(256)
void k_pool(const float* __restrict__ h, const int* __restrict__ batch,
            float* __restrict__ pool) {
    int g = blockIdx.x;
    auto lb = [&](int v) {
        int lo = 0, hi = NN;
        while (lo < hi) {
            int m = (lo + hi) >> 1;
            if (batch[m] < v) lo = m + 1; else hi = m;
        }
        return lo;
    };
    int st = lb(g), en = lb(g + 1);
    int col = threadIdx.x & 63, chunk = threadIdx.x >> 6;
    float acc = 0.f;
    for (int n = st + chunk; n < en; n += 4) acc += h[(size_t)n * 64 + col];
    __shared__ float s[256];
    s[threadIdx.x] = acc;
    __syncthreads();
    if (chunk == 0) {
        float tot = s[col] + s[64 + col] + s[128 + col] + s[192 + col];
        int c = en - st;
        pool[g * 64 + col] = tot / (float)(c > 1 ? c : 1);
    }
}

// ---- classifier: out[g][j] = cls_b[j] + pool[g] @ cls_w[:,j]   (pool already mean)
__global__ __launch_bounds__(256)
void k_final(const float* __restrict__ pool, const float* __restrict__ cw,
             const float* __restrict__ cb, float* __restrict__ out) {
    int t = blockIdx.x * blockDim.x + threadIdx.x;
    if (t >= NG * 10) return;
    int g = t / 10, j = t % 10;
    float acc = 0.f;
#pragma unroll
    for (int k = 0; k < 64; k++) acc += pool[g * 64 + k] * cw[k * 10 + j];
    out[t] = cb[j] + acc;
}

extern "C" void kernel_launch(void* const* d_in, const int* in_sizes, int n_in,
                              void* d_out, int out_size, void* d_ws, size_t ws_size,
                              hipStream_t stream) {
    const int* x      = (const int*)d_in[0];
    const int* ei     = (const int*)d_in[1];
    const int* et     = (const int*)d_in[2];
    const int* batch  = (const int*)d_in[3];
    const float* se   = (const float*)d_in[4];
    const float* ce   = (const float*)d_in[5];
    const float* pw   = (const float*)d_in[6];
    const float* pb   = (const float*)d_in[7];
    const float* w1   = (const float*)d_in[8];
    const float* root1= (const float*)d_in[9];
    const float* b1   = (const float*)d_in[10];
    const float* w2   = (const float*)d_in[11];
    const float* root2= (const float*)d_in[12];
    const float* b2   = (const float*)d_in[13];
    const float* cw   = (const float*)d_in[14];
    const float* cb   = (const float*)d_in[15];
    float* out = (float*)d_out;

    char* ws = (char*)d_ws;
    float* agg   = (float*)(ws + AGG_OFF);
    int*   cur   = (int*)(ws + CUR_OFF);     // histogram, then cursor (== segment end after fill)
    int*   start = (int*)(ws + START_OFF);
    int*   csum  = (int*)(ws + CSUM_OFF);
    int*   esrc  = (int*)(ws + ESRC_OFF);
    float* pool  = (float*)(ws + POOL_OFF);
    float* h0    = (float*)(ws + H0_OFF);
    float* h1    = (float*)(ws + H1_OFF);
    float* h2    = (float*)(ws + H2_OFF);

    // zero the histogram only
    hipMemsetAsync(cur, 0, (size_t)NSEG * 4, stream);

    k_embed_pre<<<(NN + 255) / 256, 256, 0, stream>>>(x, se, ce, pw, pb, h0);

    // CSR build
    k_count<<<(NE + 255) / 256, 256, 0, stream>>>(ei, et, cur);
    k_chunksum<<<NCHUNK, 256, 0, stream>>>(cur, csum);
    k_chunkscan<<<1, 64, 0, stream>>>(csum);
    k_localscan<<<NCHUNK, 256, 0, stream>>>(cur, csum, start);
    k_fill<<<(NE + 255) / 256, 256, 0, stream>>>(ei, et, cur, esrc);

    // layer 1
    k_gather<32><<<(NSEG * 8 + 255) / 256, 256, 0, stream>>>(start, cur, esrc, h0, agg);
    k_combine<32><<<(NN * 16 + 255) / 256, 256, 0, stream>>>(h0, agg, start, cur, root1, w1, b1, h1);

    // layer 2
    k_gather<64><<<(NSEG * 16 + 255) / 256, 256, 0, stream>>>(start, cur, esrc, h1, agg);
    k_combine<64><<<(NN * 16 + 255) / 256, 256, 0, stream>>>(h1, agg, start, cur, root2, w2, b2, h2);

    // pooling + classifier
    k_pool<<<NG, 256, 0, stream>>>(h2, batch, pool);
    k_final<<<(NG * 10 + 255) / 256, 256, 0, stream>>>(pool, cw, cb, out);
}